// Round 3
// baseline (590.751 us; speedup 1.0000x reference)
//
#include <hip/hip_runtime.h>

#define NB_MAX 1024
#define BSHIFT 7
#define BNODES 128
#define BMASK 127
#define CAP 6144
#define PB_T 512
#define PB_EPB (PB_T * 16)
#define TPB 256

// ---------------- index dtype detection ----------------
__global__ void detect_kernel(const unsigned int* __restrict__ w, int* __restrict__ flag) {
    __shared__ int any;
    if (threadIdx.x == 0) any = 0;
    __syncthreads();
    int nz = 0;
    for (int k = threadIdx.x; k < 1024; k += blockDim.x)
        if (w[2 * k + 1] != 0u) nz = 1;
    if (nz) atomicOr(&any, 1);
    __syncthreads();
    if (threadIdx.x == 0) *flag = (any == 0) ? 1 : 0;  // 1 => int64
}

__global__ void zero_kernel(int* __restrict__ p, int n) {
    int i = blockIdx.x * blockDim.x + threadIdx.x;
    if (i < n) p[i] = 0;
}

// ---------------- bucketed edge placement ----------------
// pairs[b*CAP + r] = (src << 7) | (dst & 127), bucket b = dst >> 7.
// Per-block LDS histogram -> one global atomic per (block,bucket) -> rank via LDS.
__global__ __launch_bounds__(PB_T) void bucket_place_kernel(
    const void* __restrict__ ei, const int* __restrict__ flag,
    int* __restrict__ gcur, unsigned* __restrict__ pairs, int E, int nb) {
    __shared__ int cnt[NB_MAX];
    __shared__ int base[NB_MAX];
    const bool is64 = (*flag != 0);
    const long long* e64 = (const long long*)ei;
    const int* e32 = (const int*)ei;
    int e0 = blockIdx.x * PB_EPB;
    for (int b = threadIdx.x; b < nb; b += PB_T) cnt[b] = 0;
    __syncthreads();
    for (int i = threadIdx.x; i < PB_EPB; i += PB_T) {
        int e = e0 + i;
        if (e >= E) break;
        int d = is64 ? (int)e64[E + e] : e32[E + e];
        atomicAdd(&cnt[d >> BSHIFT], 1);
    }
    __syncthreads();
    for (int b = threadIdx.x; b < nb; b += PB_T) {
        int c = cnt[b];
        base[b] = c ? atomicAdd(&gcur[b], c) : 0;
        cnt[b] = 0;
    }
    __syncthreads();
    for (int i = threadIdx.x; i < PB_EPB; i += PB_T) {
        int e = e0 + i;
        if (e >= E) break;
        int s, d;
        if (is64) { s = (int)e64[e]; d = (int)e64[E + e]; }
        else      { s = e32[e];      d = e32[E + e]; }
        int b = d >> BSHIFT;
        int r = atomicAdd(&cnt[b], 1) + base[b];
        if (r < CAP) pairs[(size_t)b * CAP + r] = ((unsigned)s << BSHIFT) | (unsigned)(d & BMASK);
    }
}

// ---------------- per-bucket degree -> dinv (no global atomics) ----------------
__global__ __launch_bounds__(TPB) void deg_kernel(
    const unsigned* __restrict__ pairs, const int* __restrict__ gcur,
    float* __restrict__ dinv, int N) {
    __shared__ int dc[BNODES];
    int b = blockIdx.x;
    if (threadIdx.x < BNODES) dc[threadIdx.x] = 0;
    __syncthreads();
    int cnt = gcur[b]; if (cnt > CAP) cnt = CAP;
    const unsigned* sl = pairs + (size_t)b * CAP;
    for (int i = threadIdx.x; i < cnt; i += TPB)
        atomicAdd(&dc[sl[i] & BMASK], 1);
    __syncthreads();
    if (threadIdx.x < BNODES) {
        int node = (b << BSHIFT) + threadIdx.x;
        if (node < N) dinv[node] = rsqrtf((float)(dc[threadIdx.x] + 1));  // +1 self-loop
    }
}

// ---------------- layer 1 GEMM: hs1 = dinv * (x @ W1) ----------------
__global__ __launch_bounds__(TPB) void gemm1_kernel(
    const float* __restrict__ x, const float* __restrict__ W,
    const float* __restrict__ dinv, float* __restrict__ hs, int N) {
    __shared__ float Ws[128 * 16];
    for (int i = threadIdx.x; i < 128 * 16; i += blockDim.x) Ws[i] = W[i];
    __syncthreads();
    int n = blockIdx.x * blockDim.x + threadIdx.x;
    if (n >= N) return;
    const float4* xp = (const float4*)(x + (size_t)n * 128);
    float a[16];
#pragma unroll
    for (int j = 0; j < 16; ++j) a[j] = 0.f;
#pragma unroll 4
    for (int k4 = 0; k4 < 32; ++k4) {
        float4 xv = xp[k4];
        const float* wr = &Ws[k4 * 64];
#pragma unroll
        for (int j = 0; j < 16; ++j) a[j] += xv.x * wr[j];
#pragma unroll
        for (int j = 0; j < 16; ++j) a[j] += xv.y * wr[16 + j];
#pragma unroll
        for (int j = 0; j < 16; ++j) a[j] += xv.z * wr[32 + j];
#pragma unroll
        for (int j = 0; j < 16; ++j) a[j] += xv.w * wr[48 + j];
    }
    float sc = dinv[n];
    float4* hp = (float4*)(hs + (size_t)n * 16);
#pragma unroll
    for (int j4 = 0; j4 < 4; ++j4) {
        float4 v;
        v.x = a[j4 * 4 + 0] * sc; v.y = a[j4 * 4 + 1] * sc;
        v.z = a[j4 * 4 + 2] * sc; v.w = a[j4 * 4 + 3] * sc;
        hp[j4] = v;
    }
}

// ---------------- bucket aggregate 1 + fused layer2 ----------------
// 64 lanes = 4 edges x 16 features; LDS accumulate (padded stride 17).
__global__ __launch_bounds__(TPB) void agg1_kernel(
    const float* __restrict__ hs1, const unsigned* __restrict__ pairs,
    const int* __restrict__ gcur, const float* __restrict__ dinv,
    const float* __restrict__ W2, const float* __restrict__ b1,
    float* __restrict__ hs2, int N) {
    __shared__ float acc[BNODES * 17];
    __shared__ float Ws[16 * 7];
    __shared__ float bs[16];
    int tid = threadIdx.x;
    for (int i = tid; i < BNODES * 17; i += TPB) acc[i] = 0.f;
    if (tid < 112) Ws[tid] = W2[tid];
    if (tid < 16) bs[tid] = b1[tid];
    __syncthreads();
    int b = blockIdx.x;
    int cnt = gcur[b]; if (cnt > CAP) cnt = CAP;
    const unsigned* sl = pairs + (size_t)b * CAP;
    int wid = tid >> 6, lane = tid & 63, sub = lane >> 4, f = lane & 15;
    for (int i = wid * 4 + sub; i < cnt; i += 16) {
        unsigned val = sl[i];
        int s = val >> BSHIFT, l = val & BMASK;
        atomicAdd(&acc[l * 17 + f], hs1[(size_t)s * 16 + f]);
    }
    __syncthreads();
    if (tid < BNODES) {
        int node = (b << BSHIFT) + tid;
        if (node < N) {
            float sc = dinv[node];
            const float* selfp = hs1 + (size_t)node * 16;
            float v[16];
#pragma unroll
            for (int j = 0; j < 16; ++j) {
                float a = acc[tid * 17 + j] + selfp[j];
                v[j] = fmaxf(0.f, sc * a + bs[j]);
            }
            float h[7];
#pragma unroll
            for (int j = 0; j < 7; ++j) h[j] = 0.f;
#pragma unroll
            for (int i = 0; i < 16; ++i)
#pragma unroll
                for (int j = 0; j < 7; ++j) h[j] += v[i] * Ws[i * 7 + j];
            float* hp = hs2 + (size_t)node * 8;
#pragma unroll
            for (int j = 0; j < 7; ++j) hp[j] = h[j] * sc;
            hp[7] = 0.f;
        }
    }
}

// ---------------- bucket aggregate 2 + fused bias/log-softmax ----------------
// 64 lanes = 8 edges x 8 features; LDS accumulate (padded stride 9).
__global__ __launch_bounds__(TPB) void agg2_kernel(
    const float* __restrict__ hs2, const unsigned* __restrict__ pairs,
    const int* __restrict__ gcur, const float* __restrict__ dinv,
    const float* __restrict__ b2, float* __restrict__ out, int N) {
    __shared__ float acc[BNODES * 9];
    __shared__ float bs[8];
    int tid = threadIdx.x;
    for (int i = tid; i < BNODES * 9; i += TPB) acc[i] = 0.f;
    if (tid < 7) bs[tid] = b2[tid];
    __syncthreads();
    int b = blockIdx.x;
    int cnt = gcur[b]; if (cnt > CAP) cnt = CAP;
    const unsigned* sl = pairs + (size_t)b * CAP;
    int wid = tid >> 6, lane = tid & 63, sub = lane >> 3, f = lane & 7;
    for (int i = wid * 8 + sub; i < cnt; i += 32) {
        unsigned val = sl[i];
        int s = val >> BSHIFT, l = val & BMASK;
        atomicAdd(&acc[l * 9 + f], hs2[(size_t)s * 8 + f]);
    }
    __syncthreads();
    if (tid < BNODES) {
        int node = (b << BSHIFT) + tid;
        if (node < N) {
            float sc = dinv[node];
            const float* selfp = hs2 + (size_t)node * 8;
            float v[7];
#pragma unroll
            for (int j = 0; j < 7; ++j)
                v[j] = sc * (acc[tid * 9 + j] + selfp[j]) + bs[j];
            float m = v[0];
#pragma unroll
            for (int j = 1; j < 7; ++j) m = fmaxf(m, v[j]);
            float ssum = 0.f;
#pragma unroll
            for (int j = 0; j < 7; ++j) ssum += __expf(v[j] - m);
            float l = m + __logf(ssum);
            float* op = out + (size_t)node * 7;
#pragma unroll
            for (int j = 0; j < 7; ++j) op[j] = v[j] - l;
        }
    }
}

extern "C" void kernel_launch(void* const* d_in, const int* in_sizes, int n_in,
                              void* d_out, int out_size, void* d_ws, size_t ws_size,
                              hipStream_t stream) {
    const float* x  = (const float*)d_in[0];
    const void*  ei = d_in[1];
    const float* W1 = (const float*)d_in[2];
    const float* b1 = (const float*)d_in[3];
    const float* W2 = (const float*)d_in[4];
    const float* b2 = (const float*)d_in[5];
    float* out = (float*)d_out;

    const int Hh  = in_sizes[3];            // 16
    const int Fin = in_sizes[2] / Hh;       // 128
    const int N   = in_sizes[0] / Fin;      // 100000
    const long long twoE = in_sizes[1];
    const int E = (int)(twoE / 2);          // 3200000
    const int nb = (N + BNODES - 1) >> BSHIFT;  // 782 buckets of 128 nodes
    (void)n_in; (void)out_size; (void)ws_size;

    char* p = (char*)d_ws;
    auto alloc = [&](size_t bytes) {
        char* r = p;
        p += (bytes + 63) & ~(size_t)63;
        return r;
    };
    int*      flag  = (int*)alloc(sizeof(int));
    int*      gcur  = (int*)alloc(sizeof(int) * (size_t)nb);
    unsigned* pairs = (unsigned*)alloc(sizeof(unsigned) * (size_t)nb * CAP);  // ~19.2 MB
    float*    dinv  = (float*)alloc(sizeof(float) * (size_t)N);
    float*    hs1   = (float*)alloc(sizeof(float) * (size_t)N * 16);
    float*    hs2   = (float*)alloc(sizeof(float) * (size_t)N * 8);

    detect_kernel<<<1, 256, 0, stream>>>((const unsigned int*)ei, flag);
    zero_kernel<<<(nb + TPB - 1) / TPB, TPB, 0, stream>>>(gcur, nb);
    bucket_place_kernel<<<(E + PB_EPB - 1) / PB_EPB, PB_T, 0, stream>>>(
        ei, flag, gcur, pairs, E, nb);
    deg_kernel<<<nb, TPB, 0, stream>>>(pairs, gcur, dinv, N);
    gemm1_kernel<<<(N + TPB - 1) / TPB, TPB, 0, stream>>>(x, W1, dinv, hs1, N);
    agg1_kernel<<<nb, TPB, 0, stream>>>(hs1, pairs, gcur, dinv, W2, b1, hs2, N);
    agg2_kernel<<<nb, TPB, 0, stream>>>(hs2, pairs, gcur, dinv, b2, out, N);
}

// Round 4
// 184.863 us; speedup vs baseline: 3.1956x; 3.1956x over previous
//
#include <hip/hip_runtime.h>

#define NB_MAX 1024
#define BSHIFT 7
#define BNODES 128
#define BMASK 127
#define CAP 6144
#define PB_T 512
#define PB_EPB (PB_T * 16)
#define TPB 256

// ---------------- index dtype detection ----------------
__global__ void detect_kernel(const unsigned int* __restrict__ w, int* __restrict__ flag) {
    __shared__ int any;
    if (threadIdx.x == 0) any = 0;
    __syncthreads();
    int nz = 0;
    for (int k = threadIdx.x; k < 1024; k += blockDim.x)
        if (w[2 * k + 1] != 0u) nz = 1;
    if (nz) atomicOr(&any, 1);
    __syncthreads();
    if (threadIdx.x == 0) *flag = (any == 0) ? 1 : 0;  // 1 => int64
}

__global__ void zero_kernel(int* __restrict__ p, int n) {
    int i = blockIdx.x * blockDim.x + threadIdx.x;
    if (i < n) p[i] = 0;
}

// ---------------- bucketed edge placement ----------------
// pairs[b*CAP + r] = (src << 7) | (dst & 127), bucket b = dst >> 7.
__global__ __launch_bounds__(PB_T) void bucket_place_kernel(
    const void* __restrict__ ei, const int* __restrict__ flag,
    int* __restrict__ gcur, unsigned* __restrict__ pairs, int E, int nb) {
    __shared__ int cnt[NB_MAX];
    __shared__ int base[NB_MAX];
    const bool is64 = (*flag != 0);
    const long long* e64 = (const long long*)ei;
    const int* e32 = (const int*)ei;
    int e0 = blockIdx.x * PB_EPB;
    for (int b = threadIdx.x; b < nb; b += PB_T) cnt[b] = 0;
    __syncthreads();
    for (int i = threadIdx.x; i < PB_EPB; i += PB_T) {
        int e = e0 + i;
        if (e >= E) break;
        int d = is64 ? (int)e64[E + e] : e32[E + e];
        atomicAdd(&cnt[d >> BSHIFT], 1);
    }
    __syncthreads();
    for (int b = threadIdx.x; b < nb; b += PB_T) {
        int c = cnt[b];
        base[b] = c ? atomicAdd(&gcur[b], c) : 0;
        cnt[b] = 0;
    }
    __syncthreads();
    for (int i = threadIdx.x; i < PB_EPB; i += PB_T) {
        int e = e0 + i;
        if (e >= E) break;
        int s, d;
        if (is64) { s = (int)e64[e]; d = (int)e64[E + e]; }
        else      { s = e32[e];      d = e32[E + e]; }
        int b = d >> BSHIFT;
        int r = atomicAdd(&cnt[b], 1) + base[b];
        if (r < CAP) pairs[(size_t)b * CAP + r] = ((unsigned)s << BSHIFT) | (unsigned)(d & BMASK);
    }
}

// ---------------- bucket base offsets (exclusive scan of bucket sizes) ----------------
__global__ __launch_bounds__(1024) void scanb_kernel(const int* __restrict__ gcur,
                                                     int* __restrict__ bbase, int nb) {
    __shared__ int sh[1024];
    int t = threadIdx.x;
    int v = 0;
    if (t < nb) { v = gcur[t]; if (v > CAP) v = CAP; }
    sh[t] = v;
    __syncthreads();
    for (int off = 1; off < 1024; off <<= 1) {
        int u = (t >= off) ? sh[t - off] : 0;
        __syncthreads();
        sh[t] += u;
        __syncthreads();
    }
    if (t < nb) bbase[t] = sh[t] - v;  // exclusive
}

// ---------------- within-bucket counting sort -> per-node CSR + deg + dinv ----------------
__global__ __launch_bounds__(TPB) void csr_build_kernel(
    const unsigned* __restrict__ pairs, const int* __restrict__ gcur,
    const int* __restrict__ bbase, int* __restrict__ csr,
    int* __restrict__ row, int* __restrict__ degA, float* __restrict__ dinv, int N) {
    __shared__ int hist[BNODES];
    __shared__ int sc[BNODES];
    __shared__ int cur[BNODES];
    int tid = threadIdx.x;
    int b = blockIdx.x;
    if (tid < BNODES) hist[tid] = 0;
    __syncthreads();
    int cnt = gcur[b]; if (cnt > CAP) cnt = CAP;
    int base = bbase[b];
    const unsigned* sl = pairs + (size_t)b * CAP;
    for (int i = tid; i < cnt; i += TPB)
        atomicAdd(&hist[sl[i] & BMASK], 1);
    __syncthreads();
    if (tid < BNODES) sc[tid] = hist[tid];
    __syncthreads();
    for (int off = 1; off < BNODES; off <<= 1) {
        int u = (tid < BNODES && tid >= off) ? sc[tid - off] : 0;
        __syncthreads();
        if (tid < BNODES) sc[tid] += u;
        __syncthreads();
    }
    if (tid < BNODES) {
        int excl = sc[tid] - hist[tid];
        sc[tid] = excl;          // repurpose as exclusive prefix
        cur[tid] = 0;
        int node = (b << BSHIFT) + tid;
        if (node < N) {
            row[node]  = base + excl;
            degA[node] = hist[tid];
            dinv[node] = rsqrtf((float)(hist[tid] + 1));  // +1 self-loop
        }
    }
    __syncthreads();
    for (int i = tid; i < cnt; i += TPB) {
        unsigned val = sl[i];
        int l = val & BMASK;
        int r = atomicAdd(&cur[l], 1);
        csr[base + sc[l] + r] = (int)(val >> BSHIFT);
    }
}

// ---------------- layer 1 GEMM: hs1 = dinv * (x @ W1) ----------------
__global__ __launch_bounds__(TPB) void gemm1_kernel(
    const float* __restrict__ x, const float* __restrict__ W,
    const float* __restrict__ dinv, float* __restrict__ hs, int N) {
    __shared__ float Ws[128 * 16];
    for (int i = threadIdx.x; i < 128 * 16; i += blockDim.x) Ws[i] = W[i];
    __syncthreads();
    int n = blockIdx.x * blockDim.x + threadIdx.x;
    if (n >= N) return;
    const float4* xp = (const float4*)(x + (size_t)n * 128);
    float a[16];
#pragma unroll
    for (int j = 0; j < 16; ++j) a[j] = 0.f;
#pragma unroll 4
    for (int k4 = 0; k4 < 32; ++k4) {
        float4 xv = xp[k4];
        const float* wr = &Ws[k4 * 64];
#pragma unroll
        for (int j = 0; j < 16; ++j) a[j] += xv.x * wr[j];
#pragma unroll
        for (int j = 0; j < 16; ++j) a[j] += xv.y * wr[16 + j];
#pragma unroll
        for (int j = 0; j < 16; ++j) a[j] += xv.z * wr[32 + j];
#pragma unroll
        for (int j = 0; j < 16; ++j) a[j] += xv.w * wr[48 + j];
    }
    float sc = dinv[n];
    float4* hp = (float4*)(hs + (size_t)n * 16);
#pragma unroll
    for (int j4 = 0; j4 < 4; ++j4) {
        float4 v;
        v.x = a[j4 * 4 + 0] * sc; v.y = a[j4 * 4 + 1] * sc;
        v.z = a[j4 * 4 + 2] * sc; v.w = a[j4 * 4 + 3] * sc;
        hp[j4] = v;
    }
}

// ---------------- agg1: per-node register gather (2 lanes/node) + fused layer2 ----------------
__global__ __launch_bounds__(TPB) void agg1_kernel(
    const float* __restrict__ hs1, const int* __restrict__ csr,
    const int* __restrict__ row, const int* __restrict__ degA,
    const float* __restrict__ dinv, const float* __restrict__ W2,
    const float* __restrict__ b1, float* __restrict__ hs2, int N) {
    __shared__ float Ws[112];
    __shared__ float bs[16];
    int tid = threadIdx.x;
    if (tid < 112) Ws[tid] = W2[tid];
    if (tid < 16) bs[tid] = b1[tid];
    __syncthreads();
    int g = blockIdx.x * TPB + tid;
    int n = g >> 1, half = g & 1;
    int st = 0, cnt = 0;
    if (n < N) { st = row[n]; cnt = degA[n]; }
    const float4* H = (const float4*)hs1;
    float4 a0 = {0,0,0,0}, a1 = a0, a2 = a0, a3 = a0;
    int i = st + half, end = st + cnt;
    for (; i + 2 < end; i += 4) {
        int s0 = csr[i], s1 = csr[i + 2];
        const float4* p0 = H + (size_t)s0 * 4;
        const float4* p1 = H + (size_t)s1 * 4;
        float4 q0 = p0[0], q1 = p0[1], q2 = p0[2], q3 = p0[3];
        float4 r0 = p1[0], r1 = p1[1], r2 = p1[2], r3 = p1[3];
        a0.x += q0.x; a0.y += q0.y; a0.z += q0.z; a0.w += q0.w;
        a1.x += q1.x; a1.y += q1.y; a1.z += q1.z; a1.w += q1.w;
        a2.x += q2.x; a2.y += q2.y; a2.z += q2.z; a2.w += q2.w;
        a3.x += q3.x; a3.y += q3.y; a3.z += q3.z; a3.w += q3.w;
        a0.x += r0.x; a0.y += r0.y; a0.z += r0.z; a0.w += r0.w;
        a1.x += r1.x; a1.y += r1.y; a1.z += r1.z; a1.w += r1.w;
        a2.x += r2.x; a2.y += r2.y; a2.z += r2.z; a2.w += r2.w;
        a3.x += r3.x; a3.y += r3.y; a3.z += r3.z; a3.w += r3.w;
    }
    if (i < end) {
        int s0 = csr[i];
        const float4* p0 = H + (size_t)s0 * 4;
        float4 q0 = p0[0], q1 = p0[1], q2 = p0[2], q3 = p0[3];
        a0.x += q0.x; a0.y += q0.y; a0.z += q0.z; a0.w += q0.w;
        a1.x += q1.x; a1.y += q1.y; a1.z += q1.z; a1.w += q1.w;
        a2.x += q2.x; a2.y += q2.y; a2.z += q2.z; a2.w += q2.w;
        a3.x += q3.x; a3.y += q3.y; a3.z += q3.z; a3.w += q3.w;
    }
    float acc[16] = {a0.x, a0.y, a0.z, a0.w, a1.x, a1.y, a1.z, a1.w,
                     a2.x, a2.y, a2.z, a2.w, a3.x, a3.y, a3.z, a3.w};
#pragma unroll
    for (int j = 0; j < 16; ++j) acc[j] += __shfl_xor(acc[j], 1);
    if (half == 0 && n < N) {
        float sc = dinv[n];
        const float* selfp = hs1 + (size_t)n * 16;
        float v[16];
#pragma unroll
        for (int j = 0; j < 16; ++j)
            v[j] = fmaxf(0.f, sc * (acc[j] + selfp[j]) + bs[j]);
        float h[7];
#pragma unroll
        for (int j = 0; j < 7; ++j) h[j] = 0.f;
#pragma unroll
        for (int k = 0; k < 16; ++k)
#pragma unroll
            for (int j = 0; j < 7; ++j) h[j] += v[k] * Ws[k * 7 + j];
        float4 o0, o1;
        o0.x = h[0] * sc; o0.y = h[1] * sc; o0.z = h[2] * sc; o0.w = h[3] * sc;
        o1.x = h[4] * sc; o1.y = h[5] * sc; o1.z = h[6] * sc; o1.w = 0.f;
        float4* hp = (float4*)(hs2 + (size_t)n * 8);
        hp[0] = o0; hp[1] = o1;
    }
}

// ---------------- agg2: per-node register gather (2 lanes/node) + bias/log-softmax ----------------
__global__ __launch_bounds__(TPB) void agg2_kernel(
    const float* __restrict__ hs2, const int* __restrict__ csr,
    const int* __restrict__ row, const int* __restrict__ degA,
    const float* __restrict__ dinv, const float* __restrict__ b2,
    float* __restrict__ out, int N) {
    __shared__ float bs[8];
    if (threadIdx.x < 7) bs[threadIdx.x] = b2[threadIdx.x];
    __syncthreads();
    int g = blockIdx.x * TPB + threadIdx.x;
    int n = g >> 1, half = g & 1;
    int st = 0, cnt = 0;
    if (n < N) { st = row[n]; cnt = degA[n]; }
    const float4* H = (const float4*)hs2;
    float4 a0 = {0,0,0,0}, a1 = a0;
    int i = st + half, end = st + cnt;
    for (; i + 2 < end; i += 4) {
        int s0 = csr[i], s1 = csr[i + 2];
        const float4* p0 = H + (size_t)s0 * 2;
        const float4* p1 = H + (size_t)s1 * 2;
        float4 q0 = p0[0], q1 = p0[1];
        float4 r0 = p1[0], r1 = p1[1];
        a0.x += q0.x; a0.y += q0.y; a0.z += q0.z; a0.w += q0.w;
        a1.x += q1.x; a1.y += q1.y; a1.z += q1.z;
        a0.x += r0.x; a0.y += r0.y; a0.z += r0.z; a0.w += r0.w;
        a1.x += r1.x; a1.y += r1.y; a1.z += r1.z;
    }
    if (i < end) {
        int s0 = csr[i];
        const float4* p0 = H + (size_t)s0 * 2;
        float4 q0 = p0[0], q1 = p0[1];
        a0.x += q0.x; a0.y += q0.y; a0.z += q0.z; a0.w += q0.w;
        a1.x += q1.x; a1.y += q1.y; a1.z += q1.z;
    }
    float acc[7] = {a0.x, a0.y, a0.z, a0.w, a1.x, a1.y, a1.z};
#pragma unroll
    for (int j = 0; j < 7; ++j) acc[j] += __shfl_xor(acc[j], 1);
    if (half == 0 && n < N) {
        float sc = dinv[n];
        const float* selfp = hs2 + (size_t)n * 8;
        float v[7];
#pragma unroll
        for (int j = 0; j < 7; ++j)
            v[j] = sc * (acc[j] + selfp[j]) + bs[j];
        float m = v[0];
#pragma unroll
        for (int j = 1; j < 7; ++j) m = fmaxf(m, v[j]);
        float ssum = 0.f;
#pragma unroll
        for (int j = 0; j < 7; ++j) ssum += __expf(v[j] - m);
        float l = m + __logf(ssum);
        float* op = out + (size_t)n * 7;
#pragma unroll
        for (int j = 0; j < 7; ++j) op[j] = v[j] - l;
    }
}

extern "C" void kernel_launch(void* const* d_in, const int* in_sizes, int n_in,
                              void* d_out, int out_size, void* d_ws, size_t ws_size,
                              hipStream_t stream) {
    const float* x  = (const float*)d_in[0];
    const void*  ei = d_in[1];
    const float* W1 = (const float*)d_in[2];
    const float* b1 = (const float*)d_in[3];
    const float* W2 = (const float*)d_in[4];
    const float* b2 = (const float*)d_in[5];
    float* out = (float*)d_out;

    const int Hh  = in_sizes[3];            // 16
    const int Fin = in_sizes[2] / Hh;       // 128
    const int N   = in_sizes[0] / Fin;      // 100000
    const long long twoE = in_sizes[1];
    const int E = (int)(twoE / 2);          // 3200000
    const int nb = (N + BNODES - 1) >> BSHIFT;  // 782 buckets of 128 nodes
    (void)n_in; (void)out_size; (void)ws_size;

    char* p = (char*)d_ws;
    auto alloc = [&](size_t bytes) {
        char* r = p;
        p += (bytes + 63) & ~(size_t)63;
        return r;
    };
    int*      flag  = (int*)alloc(sizeof(int));
    int*      gcur  = (int*)alloc(sizeof(int) * (size_t)nb);
    int*      bbase = (int*)alloc(sizeof(int) * 1024);
    unsigned* pairs = (unsigned*)alloc(sizeof(unsigned) * (size_t)nb * CAP);  // ~19.2 MB
    int*      csr   = (int*)alloc(sizeof(int) * (size_t)E);                   // 12.8 MB
    int*      rowA  = (int*)alloc(sizeof(int) * (size_t)N);
    int*      degA  = (int*)alloc(sizeof(int) * (size_t)N);
    float*    dinv  = (float*)alloc(sizeof(float) * (size_t)N);
    float*    hs1   = (float*)alloc(sizeof(float) * (size_t)N * 16);
    float*    hs2   = (float*)alloc(sizeof(float) * (size_t)N * 8);

    detect_kernel<<<1, 256, 0, stream>>>((const unsigned int*)ei, flag);
    zero_kernel<<<(nb + TPB - 1) / TPB, TPB, 0, stream>>>(gcur, nb);
    bucket_place_kernel<<<(E + PB_EPB - 1) / PB_EPB, PB_T, 0, stream>>>(
        ei, flag, gcur, pairs, E, nb);
    scanb_kernel<<<1, 1024, 0, stream>>>(gcur, bbase, nb);
    csr_build_kernel<<<nb, TPB, 0, stream>>>(pairs, gcur, bbase, csr, rowA, degA, dinv, N);
    gemm1_kernel<<<(N + TPB - 1) / TPB, TPB, 0, stream>>>(x, W1, dinv, hs1, N);
    int aggBlk = (2 * N + TPB - 1) / TPB;
    agg1_kernel<<<aggBlk, TPB, 0, stream>>>(hs1, csr, rowA, degA, dinv, W2, b1, hs2, N);
    agg2_kernel<<<aggBlk, TPB, 0, stream>>>(hs2, csr, rowA, degA, dinv, b2, out, N);
}

// Round 5
// 153.517 us; speedup vs baseline: 3.8481x; 1.2042x over previous
//
#include <hip/hip_runtime.h>

#define NB_MAX 1024
#define BSHIFT 7
#define BNODES 128
#define BMASK 127
#define CAP 6144
#define PB_T 512
#define PB_EPB (PB_T * 16)
#define TPB 256

// ---------------- index dtype detection ----------------
__global__ void detect_kernel(const unsigned int* __restrict__ w, int* __restrict__ flag) {
    __shared__ int any;
    if (threadIdx.x == 0) any = 0;
    __syncthreads();
    int nz = 0;
    for (int k = threadIdx.x; k < 1024; k += blockDim.x)
        if (w[2 * k + 1] != 0u) nz = 1;
    if (nz) atomicOr(&any, 1);
    __syncthreads();
    if (threadIdx.x == 0) *flag = (any == 0) ? 1 : 0;  // 1 => int64
}

__global__ void zero_kernel(int* __restrict__ p, int n) {
    int i = blockIdx.x * blockDim.x + threadIdx.x;
    if (i < n) p[i] = 0;
}

// ---------------- bucketed edge placement ----------------
// pairs[b*CAP + r] = (src << 7) | (dst & 127), bucket b = dst >> 7.
__global__ __launch_bounds__(PB_T) void bucket_place_kernel(
    const void* __restrict__ ei, const int* __restrict__ flag,
    int* __restrict__ gcur, unsigned* __restrict__ pairs, int E, int nb) {
    __shared__ int cnt[NB_MAX];
    __shared__ int base[NB_MAX];
    const bool is64 = (*flag != 0);
    const long long* e64 = (const long long*)ei;
    const int* e32 = (const int*)ei;
    int e0 = blockIdx.x * PB_EPB;
    for (int b = threadIdx.x; b < nb; b += PB_T) cnt[b] = 0;
    __syncthreads();
    for (int i = threadIdx.x; i < PB_EPB; i += PB_T) {
        int e = e0 + i;
        if (e >= E) break;
        int d = is64 ? (int)e64[E + e] : e32[E + e];
        atomicAdd(&cnt[d >> BSHIFT], 1);
    }
    __syncthreads();
    for (int b = threadIdx.x; b < nb; b += PB_T) {
        int c = cnt[b];
        base[b] = c ? atomicAdd(&gcur[b], c) : 0;
        cnt[b] = 0;
    }
    __syncthreads();
    for (int i = threadIdx.x; i < PB_EPB; i += PB_T) {
        int e = e0 + i;
        if (e >= E) break;
        int s, d;
        if (is64) { s = (int)e64[e]; d = (int)e64[E + e]; }
        else      { s = e32[e];      d = e32[E + e]; }
        int b = d >> BSHIFT;
        int r = atomicAdd(&cnt[b], 1) + base[b];
        if (r < CAP) pairs[(size_t)b * CAP + r] = ((unsigned)s << BSHIFT) | (unsigned)(d & BMASK);
    }
}

// ---------------- bucket base offsets (exclusive scan of bucket sizes) ----------------
__global__ __launch_bounds__(1024) void scanb_kernel(const int* __restrict__ gcur,
                                                     int* __restrict__ bbase, int nb) {
    __shared__ int sh[1024];
    int t = threadIdx.x;
    int v = 0;
    if (t < nb) { v = gcur[t]; if (v > CAP) v = CAP; }
    sh[t] = v;
    __syncthreads();
    for (int off = 1; off < 1024; off <<= 1) {
        int u = (t >= off) ? sh[t - off] : 0;
        __syncthreads();
        sh[t] += u;
        __syncthreads();
    }
    if (t < nb) bbase[t] = sh[t] - v;  // exclusive
}

// ---------------- within-bucket counting sort -> per-node CSR (LDS-staged, coalesced write) ----------------
__global__ __launch_bounds__(TPB) void csr_build_kernel(
    const unsigned* __restrict__ pairs, const int* __restrict__ gcur,
    const int* __restrict__ bbase, int* __restrict__ csr,
    int* __restrict__ row, int* __restrict__ degA, float* __restrict__ dinv, int N) {
    __shared__ int hist[BNODES];
    __shared__ int sc[BNODES];
    __shared__ int cur[BNODES];
    __shared__ int stage[CAP];
    int tid = threadIdx.x;
    int b = blockIdx.x;
    if (tid < BNODES) hist[tid] = 0;
    __syncthreads();
    int cnt = gcur[b]; if (cnt > CAP) cnt = CAP;
    int base = bbase[b];
    const unsigned* sl = pairs + (size_t)b * CAP;
    for (int i = tid; i < cnt; i += TPB)
        atomicAdd(&hist[sl[i] & BMASK], 1);
    __syncthreads();
    if (tid < BNODES) sc[tid] = hist[tid];
    __syncthreads();
    for (int off = 1; off < BNODES; off <<= 1) {
        int u = (tid < BNODES && tid >= off) ? sc[tid - off] : 0;
        __syncthreads();
        if (tid < BNODES) sc[tid] += u;
        __syncthreads();
    }
    if (tid < BNODES) {
        int excl = sc[tid] - hist[tid];
        sc[tid] = excl;          // exclusive prefix
        cur[tid] = 0;
        int node = (b << BSHIFT) + tid;
        if (node < N) {
            row[node]  = base + excl;
            degA[node] = hist[tid];
            dinv[node] = rsqrtf((float)(hist[tid] + 1));  // +1 self-loop
        }
    }
    __syncthreads();
    // LDS scatter (sorted by local node), then coalesced global write
    for (int i = tid; i < cnt; i += TPB) {
        unsigned val = sl[i];
        int l = val & BMASK;
        int r = atomicAdd(&cur[l], 1);
        stage[sc[l] + r] = (int)(val >> BSHIFT);
    }
    __syncthreads();
    for (int i = tid; i < cnt; i += TPB)
        csr[base + i] = stage[i];
}

// ---------------- layer 1 GEMM: hs1 = dinv * (x @ W1) ----------------
__global__ __launch_bounds__(TPB) void gemm1_kernel(
    const float* __restrict__ x, const float* __restrict__ W,
    const float* __restrict__ dinv, float* __restrict__ hs, int N) {
    __shared__ float Ws[128 * 16];
    for (int i = threadIdx.x; i < 128 * 16; i += blockDim.x) Ws[i] = W[i];
    __syncthreads();
    int n = blockIdx.x * blockDim.x + threadIdx.x;
    if (n >= N) return;
    const float4* xp = (const float4*)(x + (size_t)n * 128);
    float a[16];
#pragma unroll
    for (int j = 0; j < 16; ++j) a[j] = 0.f;
#pragma unroll 4
    for (int k4 = 0; k4 < 32; ++k4) {
        float4 xv = xp[k4];
        const float* wr = &Ws[k4 * 64];
#pragma unroll
        for (int j = 0; j < 16; ++j) a[j] += xv.x * wr[j];
#pragma unroll
        for (int j = 0; j < 16; ++j) a[j] += xv.y * wr[16 + j];
#pragma unroll
        for (int j = 0; j < 16; ++j) a[j] += xv.z * wr[32 + j];
#pragma unroll
        for (int j = 0; j < 16; ++j) a[j] += xv.w * wr[48 + j];
    }
    float sc = dinv[n];
    float4* hp = (float4*)(hs + (size_t)n * 16);
#pragma unroll
    for (int j4 = 0; j4 < 4; ++j4) {
        float4 v;
        v.x = a[j4 * 4 + 0] * sc; v.y = a[j4 * 4 + 1] * sc;
        v.z = a[j4 * 4 + 2] * sc; v.w = a[j4 * 4 + 3] * sc;
        hp[j4] = v;
    }
}

// ---------------- agg1: per-node register gather (4 lanes/node) + fused layer2 ----------------
__global__ __launch_bounds__(TPB) void agg1_kernel(
    const float* __restrict__ hs1, const int* __restrict__ csr,
    const int* __restrict__ row, const int* __restrict__ degA,
    const float* __restrict__ dinv, const float* __restrict__ W2,
    const float* __restrict__ b1, float* __restrict__ hs2, int N) {
    __shared__ float Ws[112];
    __shared__ float bs[16];
    int tid = threadIdx.x;
    if (tid < 112) Ws[tid] = W2[tid];
    if (tid < 16) bs[tid] = b1[tid];
    __syncthreads();
    int g = blockIdx.x * TPB + tid;
    int n = g >> 2, quarter = g & 3;
    int st = 0, cnt = 0;
    if (n < N) { st = row[n]; cnt = degA[n]; }
    const float4* H = (const float4*)hs1;
    float4 a0 = {0,0,0,0}, a1 = a0, a2 = a0, a3 = a0;
    int i = st + quarter, end = st + cnt;
    for (; i + 4 < end; i += 8) {
        int s0 = csr[i], s1 = csr[i + 4];
        const float4* p0 = H + (size_t)s0 * 4;
        const float4* p1 = H + (size_t)s1 * 4;
        float4 q0 = p0[0], q1 = p0[1], q2 = p0[2], q3 = p0[3];
        float4 r0 = p1[0], r1 = p1[1], r2 = p1[2], r3 = p1[3];
        a0.x += q0.x; a0.y += q0.y; a0.z += q0.z; a0.w += q0.w;
        a1.x += q1.x; a1.y += q1.y; a1.z += q1.z; a1.w += q1.w;
        a2.x += q2.x; a2.y += q2.y; a2.z += q2.z; a2.w += q2.w;
        a3.x += q3.x; a3.y += q3.y; a3.z += q3.z; a3.w += q3.w;
        a0.x += r0.x; a0.y += r0.y; a0.z += r0.z; a0.w += r0.w;
        a1.x += r1.x; a1.y += r1.y; a1.z += r1.z; a1.w += r1.w;
        a2.x += r2.x; a2.y += r2.y; a2.z += r2.z; a2.w += r2.w;
        a3.x += r3.x; a3.y += r3.y; a3.z += r3.z; a3.w += r3.w;
    }
    if (i < end) {
        int s0 = csr[i];
        const float4* p0 = H + (size_t)s0 * 4;
        float4 q0 = p0[0], q1 = p0[1], q2 = p0[2], q3 = p0[3];
        a0.x += q0.x; a0.y += q0.y; a0.z += q0.z; a0.w += q0.w;
        a1.x += q1.x; a1.y += q1.y; a1.z += q1.z; a1.w += q1.w;
        a2.x += q2.x; a2.y += q2.y; a2.z += q2.z; a2.w += q2.w;
        a3.x += q3.x; a3.y += q3.y; a3.z += q3.z; a3.w += q3.w;
    }
    float acc[16] = {a0.x, a0.y, a0.z, a0.w, a1.x, a1.y, a1.z, a1.w,
                     a2.x, a2.y, a2.z, a2.w, a3.x, a3.y, a3.z, a3.w};
#pragma unroll
    for (int j = 0; j < 16; ++j) {
        acc[j] += __shfl_xor(acc[j], 1);
        acc[j] += __shfl_xor(acc[j], 2);
    }
    if (quarter == 0 && n < N) {
        float sc = dinv[n];
        const float* selfp = hs1 + (size_t)n * 16;
        float v[16];
#pragma unroll
        for (int j = 0; j < 16; ++j)
            v[j] = fmaxf(0.f, sc * (acc[j] + selfp[j]) + bs[j]);
        float h[7];
#pragma unroll
        for (int j = 0; j < 7; ++j) h[j] = 0.f;
#pragma unroll
        for (int k = 0; k < 16; ++k)
#pragma unroll
            for (int j = 0; j < 7; ++j) h[j] += v[k] * Ws[k * 7 + j];
        float4 o0, o1;
        o0.x = h[0] * sc; o0.y = h[1] * sc; o0.z = h[2] * sc; o0.w = h[3] * sc;
        o1.x = h[4] * sc; o1.y = h[5] * sc; o1.z = h[6] * sc; o1.w = 0.f;
        float4* hp = (float4*)(hs2 + (size_t)n * 8);
        hp[0] = o0; hp[1] = o1;
    }
}

// ---------------- agg2: per-node register gather (4 lanes/node) + bias/log-softmax ----------------
__global__ __launch_bounds__(TPB) void agg2_kernel(
    const float* __restrict__ hs2, const int* __restrict__ csr,
    const int* __restrict__ row, const int* __restrict__ degA,
    const float* __restrict__ dinv, const float* __restrict__ b2,
    float* __restrict__ out, int N) {
    __shared__ float bs[8];
    if (threadIdx.x < 7) bs[threadIdx.x] = b2[threadIdx.x];
    __syncthreads();
    int g = blockIdx.x * TPB + threadIdx.x;
    int n = g >> 2, quarter = g & 3;
    int st = 0, cnt = 0;
    if (n < N) { st = row[n]; cnt = degA[n]; }
    const float4* H = (const float4*)hs2;
    float4 a0 = {0,0,0,0}, a1 = a0;
    int i = st + quarter, end = st + cnt;
    for (; i + 4 < end; i += 8) {
        int s0 = csr[i], s1 = csr[i + 4];
        const float4* p0 = H + (size_t)s0 * 2;
        const float4* p1 = H + (size_t)s1 * 2;
        float4 q0 = p0[0], q1 = p0[1];
        float4 r0 = p1[0], r1 = p1[1];
        a0.x += q0.x; a0.y += q0.y; a0.z += q0.z; a0.w += q0.w;
        a1.x += q1.x; a1.y += q1.y; a1.z += q1.z;
        a0.x += r0.x; a0.y += r0.y; a0.z += r0.z; a0.w += r0.w;
        a1.x += r1.x; a1.y += r1.y; a1.z += r1.z;
    }
    if (i < end) {
        int s0 = csr[i];
        const float4* p0 = H + (size_t)s0 * 2;
        float4 q0 = p0[0], q1 = p0[1];
        a0.x += q0.x; a0.y += q0.y; a0.z += q0.z; a0.w += q0.w;
        a1.x += q1.x; a1.y += q1.y; a1.z += q1.z;
    }
    float acc[7] = {a0.x, a0.y, a0.z, a0.w, a1.x, a1.y, a1.z};
#pragma unroll
    for (int j = 0; j < 7; ++j) {
        acc[j] += __shfl_xor(acc[j], 1);
        acc[j] += __shfl_xor(acc[j], 2);
    }
    if (quarter == 0 && n < N) {
        float sc = dinv[n];
        const float* selfp = hs2 + (size_t)n * 8;
        float v[7];
#pragma unroll
        for (int j = 0; j < 7; ++j)
            v[j] = sc * (acc[j] + selfp[j]) + bs[j];
        float m = v[0];
#pragma unroll
        for (int j = 1; j < 7; ++j) m = fmaxf(m, v[j]);
        float ssum = 0.f;
#pragma unroll
        for (int j = 0; j < 7; ++j) ssum += __expf(v[j] - m);
        float l = m + __logf(ssum);
        float* op = out + (size_t)n * 7;
#pragma unroll
        for (int j = 0; j < 7; ++j) op[j] = v[j] - l;
    }
}

extern "C" void kernel_launch(void* const* d_in, const int* in_sizes, int n_in,
                              void* d_out, int out_size, void* d_ws, size_t ws_size,
                              hipStream_t stream) {
    const float* x  = (const float*)d_in[0];
    const void*  ei = d_in[1];
    const float* W1 = (const float*)d_in[2];
    const float* b1 = (const float*)d_in[3];
    const float* W2 = (const float*)d_in[4];
    const float* b2 = (const float*)d_in[5];
    float* out = (float*)d_out;

    const int Hh  = in_sizes[3];            // 16
    const int Fin = in_sizes[2] / Hh;       // 128
    const int N   = in_sizes[0] / Fin;      // 100000
    const long long twoE = in_sizes[1];
    const int E = (int)(twoE / 2);          // 3200000
    const int nb = (N + BNODES - 1) >> BSHIFT;  // 782 buckets of 128 nodes
    (void)n_in; (void)out_size; (void)ws_size;

    char* p = (char*)d_ws;
    auto alloc = [&](size_t bytes) {
        char* r = p;
        p += (bytes + 63) & ~(size_t)63;
        return r;
    };
    int*      flag  = (int*)alloc(sizeof(int));
    int*      gcur  = (int*)alloc(sizeof(int) * (size_t)nb);
    int*      bbase = (int*)alloc(sizeof(int) * 1024);
    unsigned* pairs = (unsigned*)alloc(sizeof(unsigned) * (size_t)nb * CAP);  // ~19.2 MB
    int*      csr   = (int*)alloc(sizeof(int) * (size_t)E);                   // 12.8 MB
    int*      rowA  = (int*)alloc(sizeof(int) * (size_t)N);
    int*      degA  = (int*)alloc(sizeof(int) * (size_t)N);
    float*    dinv  = (float*)alloc(sizeof(float) * (size_t)N);
    float*    hs1   = (float*)alloc(sizeof(float) * (size_t)N * 16);
    float*    hs2   = (float*)alloc(sizeof(float) * (size_t)N * 8);

    detect_kernel<<<1, 256, 0, stream>>>((const unsigned int*)ei, flag);
    zero_kernel<<<(nb + TPB - 1) / TPB, TPB, 0, stream>>>(gcur, nb);
    bucket_place_kernel<<<(E + PB_EPB - 1) / PB_EPB, PB_T, 0, stream>>>(
        ei, flag, gcur, pairs, E, nb);
    scanb_kernel<<<1, 1024, 0, stream>>>(gcur, bbase, nb);
    csr_build_kernel<<<nb, TPB, 0, stream>>>(pairs, gcur, bbase, csr, rowA, degA, dinv, N);
    gemm1_kernel<<<(N + TPB - 1) / TPB, TPB, 0, stream>>>(x, W1, dinv, hs1, N);
    int aggBlk = (4 * N + TPB - 1) / TPB;
    agg1_kernel<<<aggBlk, TPB, 0, stream>>>(hs1, csr, rowA, degA, dinv, W2, b1, hs2, N);
    agg2_kernel<<<aggBlk, TPB, 0, stream>>>(hs2, csr, rowA, degA, dinv, b2, out, N);
}

// Round 6
// 144.674 us; speedup vs baseline: 4.0833x; 1.0611x over previous
//
#include <hip/hip_runtime.h>

#define BSHIFT 7
#define BNODES 128
#define BMASK 127
#define CAP 6144
#define NB_MAX 1024
#define PT 512               // fat-kernel threads
#define P_EPB (PT * 16)      // 8192 edges per place block
#define TPB 256

// ---------------- index dtype detection + gcur zero ----------------
__global__ void detect_kernel(const unsigned int* __restrict__ w, int* __restrict__ flag,
                              int* __restrict__ gcur, int nb) {
    __shared__ int any;
    if (threadIdx.x == 0) any = 0;
    __syncthreads();
    int nz = 0;
    for (int k = threadIdx.x; k < 1024; k += blockDim.x)
        if (w[2 * k + 1] != 0u) nz = 1;
    if (nz) atomicOr(&any, 1);
    for (int i = threadIdx.x; i < nb; i += blockDim.x) gcur[i] = 0;
    __syncthreads();
    if (threadIdx.x == 0) *flag = (any == 0) ? 1 : 0;  // 1 => int64
}

// ---------------- fused: bucketed placement (write-combined) + layer-1 GEMM ----------------
// blocks [0, pb): placement. blocks [pb, pb+gb): h = x @ W1 (unscaled; dinv applied in csr_build).
// smem layout (place path): cnt@0(4096) bbs@4096(4112) cur@8208(4096) ssum@12304(2048) stage@14352(32768)
__global__ __launch_bounds__(PT) void fused_place_gemm_kernel(
    const void* __restrict__ ei, const int* __restrict__ flag,
    int* __restrict__ gcur, unsigned* __restrict__ pairs,
    const float* __restrict__ x, const float* __restrict__ W1,
    float* __restrict__ hs, int E, int nb, int pb, int N) {
    __shared__ alignas(16) char smem[47120];
    int tid = threadIdx.x;
    if ((int)blockIdx.x < pb) {
        int* cnt  = (int*)smem;                  // histogram, then per-bucket global base
        int* bbs  = (int*)(smem + 4096);         // local exclusive offsets (+ sentinel)
        int* cur  = (int*)(smem + 8208);         // scatter cursor
        int* ssum = (int*)(smem + 12304);        // scan scratch
        unsigned* stage = (unsigned*)(smem + 14352);
        const bool is64 = (*flag != 0);
        const long long* e64 = (const long long*)ei;
        const int* e32 = (const int*)ei;
        int e0 = blockIdx.x * P_EPB;
        int tot = E - e0; if (tot > P_EPB) tot = P_EPB;
        for (int b = tid; b < nb; b += PT) cnt[b] = 0;
        __syncthreads();
        // pass 1: histogram over dst
        for (int i = tid; i < tot; i += PT) {
            int e = e0 + i;
            int d = is64 ? (int)e64[E + e] : e32[E + e];
            atomicAdd(&cnt[d >> BSHIFT], 1);
        }
        __syncthreads();
        // local scan (2 bins/thread) + global reservation
        int t2 = tid * 2;
        int c0 = (t2 < nb) ? cnt[t2] : 0;
        int c1 = (t2 + 1 < nb) ? cnt[t2 + 1] : 0;
        int ts = c0 + c1;
        ssum[tid] = ts;
        __syncthreads();
        for (int off = 1; off < PT; off <<= 1) {
            int v = (tid >= off) ? ssum[tid - off] : 0;
            __syncthreads();
            ssum[tid] += v;
            __syncthreads();
        }
        int excl = ssum[tid] - ts;
        if (tid == PT - 1) bbs[nb] = ssum[PT - 1];   // sentinel = staged total
        int gb0 = 0, gb1 = 0;
        if (t2 < nb && c0) gb0 = atomicAdd(&gcur[t2], c0);
        if (t2 + 1 < nb && c1) gb1 = atomicAdd(&gcur[t2 + 1], c1);
        if (t2 < nb)     { bbs[t2] = excl;          cnt[t2] = gb0;     cur[t2] = 0; }
        if (t2 + 1 < nb) { bbs[t2 + 1] = excl + c0; cnt[t2 + 1] = gb1; cur[t2 + 1] = 0; }
        __syncthreads();
        // pass 2: scatter into LDS stage, bucket-sorted
        for (int i = tid; i < tot; i += PT) {
            int e = e0 + i;
            int s, d;
            if (is64) { s = (int)e64[e]; d = (int)e64[E + e]; }
            else      { s = e32[e];      d = e32[E + e]; }
            int b = d >> BSHIFT;
            int r = atomicAdd(&cur[b], 1);
            stage[bbs[b] + r] = ((unsigned)s << BSHIFT) | (unsigned)(d & BMASK);
        }
        __syncthreads();
        // pass 3: coalesced write of per-bucket runs (binary search for bucket)
        for (int i = tid; i < tot; i += PT) {
            int lo = 0, hi = nb;
            while (hi - lo > 1) { int mid = (lo + hi) >> 1; if (bbs[mid] <= i) lo = mid; else hi = mid; }
            int slot = cnt[lo] + (i - bbs[lo]);
            if (slot < CAP) pairs[(size_t)lo * CAP + slot] = stage[i];
        }
    } else {
        // ---- layer-1 GEMM: h = x @ W1 (unscaled) ----
        float* Ws = (float*)smem;
        for (int i = tid; i < 2048; i += PT) Ws[i] = W1[i];
        __syncthreads();
        int n = ((int)blockIdx.x - pb) * PT + tid;
        if (n >= N) return;
        const float4* xp = (const float4*)(x + (size_t)n * 128);
        float a[16];
#pragma unroll
        for (int j = 0; j < 16; ++j) a[j] = 0.f;
#pragma unroll 4
        for (int k4 = 0; k4 < 32; ++k4) {
            float4 xv = xp[k4];
            const float* wr = &Ws[k4 * 64];
#pragma unroll
            for (int j = 0; j < 16; ++j) a[j] += xv.x * wr[j];
#pragma unroll
            for (int j = 0; j < 16; ++j) a[j] += xv.y * wr[16 + j];
#pragma unroll
            for (int j = 0; j < 16; ++j) a[j] += xv.z * wr[32 + j];
#pragma unroll
            for (int j = 0; j < 16; ++j) a[j] += xv.w * wr[48 + j];
        }
        float4* hp = (float4*)(hs + (size_t)n * 16);
#pragma unroll
        for (int j4 = 0; j4 < 4; ++j4) {
            float4 v;
            v.x = a[j4 * 4 + 0]; v.y = a[j4 * 4 + 1];
            v.z = a[j4 * 4 + 2]; v.w = a[j4 * 4 + 3];
            hp[j4] = v;
        }
    }
}

// ---------------- bucket base offsets (exclusive scan of bucket sizes) ----------------
__global__ __launch_bounds__(1024) void scanb_kernel(const int* __restrict__ gcur,
                                                     int* __restrict__ bbase, int nb) {
    __shared__ int sh[1024];
    int t = threadIdx.x;
    int v = 0;
    if (t < nb) { v = gcur[t]; if (v > CAP) v = CAP; }
    sh[t] = v;
    __syncthreads();
    for (int off = 1; off < 1024; off <<= 1) {
        int u = (t >= off) ? sh[t - off] : 0;
        __syncthreads();
        sh[t] += u;
        __syncthreads();
    }
    if (t < nb) bbase[t] = sh[t] - v;  // exclusive
}

// ---------------- counting sort -> CSR + deg/dinv + in-place dinv scale of hs1 ----------------
__global__ __launch_bounds__(TPB) void csr_build_kernel(
    const unsigned* __restrict__ pairs, const int* __restrict__ gcur,
    const int* __restrict__ bbase, int* __restrict__ csr,
    int* __restrict__ row, int* __restrict__ degA, float* __restrict__ dinv,
    float* __restrict__ hs1, int N) {
    __shared__ int hist[BNODES];
    __shared__ int sc[BNODES];
    __shared__ int cur[BNODES];
    __shared__ int stage[CAP];
    int tid = threadIdx.x;
    int b = blockIdx.x;
    if (tid < BNODES) hist[tid] = 0;
    __syncthreads();
    int cnt = gcur[b]; if (cnt > CAP) cnt = CAP;
    int base = bbase[b];
    const unsigned* sl = pairs + (size_t)b * CAP;
    for (int i = tid; i < cnt; i += TPB)
        atomicAdd(&hist[sl[i] & BMASK], 1);
    __syncthreads();
    if (tid < BNODES) sc[tid] = hist[tid];
    __syncthreads();
    for (int off = 1; off < BNODES; off <<= 1) {
        int u = (tid < BNODES && tid >= off) ? sc[tid - off] : 0;
        __syncthreads();
        if (tid < BNODES) sc[tid] += u;
        __syncthreads();
    }
    if (tid < BNODES) {
        int excl = sc[tid] - hist[tid];
        sc[tid] = excl;
        cur[tid] = 0;
        int node = (b << BSHIFT) + tid;
        if (node < N) {
            row[node]  = base + excl;
            degA[node] = hist[tid];
            dinv[node] = rsqrtf((float)(hist[tid] + 1));  // +1 self-loop
        }
    }
    __syncthreads();
    for (int i = tid; i < cnt; i += TPB) {
        unsigned val = sl[i];
        int l = val & BMASK;
        int r = atomicAdd(&cur[l], 1);
        stage[sc[l] + r] = (int)(val >> BSHIFT);
    }
    __syncthreads();
    for (int i = tid; i < cnt; i += TPB)
        csr[base + i] = stage[i];
    // in-place scale: hs1[node] *= dinv[node] for this bucket (coalesced float4)
    int nodeBase = b << BSHIFT;
    for (int i = tid; i < BNODES * 4; i += TPB) {
        int ln = i >> 2;
        int node = nodeBase + ln;
        if (node < N) {
            float s = rsqrtf((float)(hist[ln] + 1));
            float4* H4 = (float4*)(hs1 + (size_t)node * 16);
            float4 v = H4[i & 3];
            v.x *= s; v.y *= s; v.z *= s; v.w *= s;
            H4[i & 3] = v;
        }
    }
}

// ---------------- agg1: per-node register gather (4 lanes/node) + fused layer2 ----------------
__global__ __launch_bounds__(TPB) void agg1_kernel(
    const float* __restrict__ hs1, const int* __restrict__ csr,
    const int* __restrict__ row, const int* __restrict__ degA,
    const float* __restrict__ dinv, const float* __restrict__ W2,
    const float* __restrict__ b1, float* __restrict__ hs2, int N) {
    __shared__ float Ws[112];
    __shared__ float bs[16];
    int tid = threadIdx.x;
    if (tid < 112) Ws[tid] = W2[tid];
    if (tid < 16) bs[tid] = b1[tid];
    __syncthreads();
    int g = blockIdx.x * TPB + tid;
    int n = g >> 2, quarter = g & 3;
    int st = 0, cnt = 0;
    if (n < N) { st = row[n]; cnt = degA[n]; }
    const float4* H = (const float4*)hs1;
    float4 a0 = {0,0,0,0}, a1 = a0, a2 = a0, a3 = a0;
    int i = st + quarter, end = st + cnt;
    for (; i + 4 < end; i += 8) {
        int s0 = csr[i], s1 = csr[i + 4];
        const float4* p0 = H + (size_t)s0 * 4;
        const float4* p1 = H + (size_t)s1 * 4;
        float4 q0 = p0[0], q1 = p0[1], q2 = p0[2], q3 = p0[3];
        float4 r0 = p1[0], r1 = p1[1], r2 = p1[2], r3 = p1[3];
        a0.x += q0.x; a0.y += q0.y; a0.z += q0.z; a0.w += q0.w;
        a1.x += q1.x; a1.y += q1.y; a1.z += q1.z; a1.w += q1.w;
        a2.x += q2.x; a2.y += q2.y; a2.z += q2.z; a2.w += q2.w;
        a3.x += q3.x; a3.y += q3.y; a3.z += q3.z; a3.w += q3.w;
        a0.x += r0.x; a0.y += r0.y; a0.z += r0.z; a0.w += r0.w;
        a1.x += r1.x; a1.y += r1.y; a1.z += r1.z; a1.w += r1.w;
        a2.x += r2.x; a2.y += r2.y; a2.z += r2.z; a2.w += r2.w;
        a3.x += r3.x; a3.y += r3.y; a3.z += r3.z; a3.w += r3.w;
    }
    if (i < end) {
        int s0 = csr[i];
        const float4* p0 = H + (size_t)s0 * 4;
        float4 q0 = p0[0], q1 = p0[1], q2 = p0[2], q3 = p0[3];
        a0.x += q0.x; a0.y += q0.y; a0.z += q0.z; a0.w += q0.w;
        a1.x += q1.x; a1.y += q1.y; a1.z += q1.z; a1.w += q1.w;
        a2.x += q2.x; a2.y += q2.y; a2.z += q2.z; a2.w += q2.w;
        a3.x += q3.x; a3.y += q3.y; a3.z += q3.z; a3.w += q3.w;
    }
    float acc[16] = {a0.x, a0.y, a0.z, a0.w, a1.x, a1.y, a1.z, a1.w,
                     a2.x, a2.y, a2.z, a2.w, a3.x, a3.y, a3.z, a3.w};
#pragma unroll
    for (int j = 0; j < 16; ++j) {
        acc[j] += __shfl_xor(acc[j], 1);
        acc[j] += __shfl_xor(acc[j], 2);
    }
    if (quarter == 0 && n < N) {
        float sc = dinv[n];
        const float* selfp = hs1 + (size_t)n * 16;
        float v[16];
#pragma unroll
        for (int j = 0; j < 16; ++j)
            v[j] = fmaxf(0.f, sc * (acc[j] + selfp[j]) + bs[j]);
        float h[7];
#pragma unroll
        for (int j = 0; j < 7; ++j) h[j] = 0.f;
#pragma unroll
        for (int k = 0; k < 16; ++k)
#pragma unroll
            for (int j = 0; j < 7; ++j) h[j] += v[k] * Ws[k * 7 + j];
        float4 o0, o1;
        o0.x = h[0] * sc; o0.y = h[1] * sc; o0.z = h[2] * sc; o0.w = h[3] * sc;
        o1.x = h[4] * sc; o1.y = h[5] * sc; o1.z = h[6] * sc; o1.w = 0.f;
        float4* hp = (float4*)(hs2 + (size_t)n * 8);
        hp[0] = o0; hp[1] = o1;
    }
}

// ---------------- agg2: per-node register gather (4 lanes/node) + bias/log-softmax ----------------
__global__ __launch_bounds__(TPB) void agg2_kernel(
    const float* __restrict__ hs2, const int* __restrict__ csr,
    const int* __restrict__ row, const int* __restrict__ degA,
    const float* __restrict__ dinv, const float* __restrict__ b2,
    float* __restrict__ out, int N) {
    __shared__ float bs[8];
    if (threadIdx.x < 7) bs[threadIdx.x] = b2[threadIdx.x];
    __syncthreads();
    int g = blockIdx.x * TPB + threadIdx.x;
    int n = g >> 2, quarter = g & 3;
    int st = 0, cnt = 0;
    if (n < N) { st = row[n]; cnt = degA[n]; }
    const float4* H = (const float4*)hs2;
    float4 a0 = {0,0,0,0}, a1 = a0;
    int i = st + quarter, end = st + cnt;
    for (; i + 4 < end; i += 8) {
        int s0 = csr[i], s1 = csr[i + 4];
        const float4* p0 = H + (size_t)s0 * 2;
        const float4* p1 = H + (size_t)s1 * 2;
        float4 q0 = p0[0], q1 = p0[1];
        float4 r0 = p1[0], r1 = p1[1];
        a0.x += q0.x; a0.y += q0.y; a0.z += q0.z; a0.w += q0.w;
        a1.x += q1.x; a1.y += q1.y; a1.z += q1.z;
        a0.x += r0.x; a0.y += r0.y; a0.z += r0.z; a0.w += r0.w;
        a1.x += r1.x; a1.y += r1.y; a1.z += r1.z;
    }
    if (i < end) {
        int s0 = csr[i];
        const float4* p0 = H + (size_t)s0 * 2;
        float4 q0 = p0[0], q1 = p0[1];
        a0.x += q0.x; a0.y += q0.y; a0.z += q0.z; a0.w += q0.w;
        a1.x += q1.x; a1.y += q1.y; a1.z += q1.z;
    }
    float acc[7] = {a0.x, a0.y, a0.z, a0.w, a1.x, a1.y, a1.z};
#pragma unroll
    for (int j = 0; j < 7; ++j) {
        acc[j] += __shfl_xor(acc[j], 1);
        acc[j] += __shfl_xor(acc[j], 2);
    }
    if (quarter == 0 && n < N) {
        float sc = dinv[n];
        const float* selfp = hs2 + (size_t)n * 8;
        float v[7];
#pragma unroll
        for (int j = 0; j < 7; ++j)
            v[j] = sc * (acc[j] + selfp[j]) + bs[j];
        float m = v[0];
#pragma unroll
        for (int j = 1; j < 7; ++j) m = fmaxf(m, v[j]);
        float ssum = 0.f;
#pragma unroll
        for (int j = 0; j < 7; ++j) ssum += __expf(v[j] - m);
        float l = m + __logf(ssum);
        float* op = out + (size_t)n * 7;
#pragma unroll
        for (int j = 0; j < 7; ++j) op[j] = v[j] - l;
    }
}

extern "C" void kernel_launch(void* const* d_in, const int* in_sizes, int n_in,
                              void* d_out, int out_size, void* d_ws, size_t ws_size,
                              hipStream_t stream) {
    const float* x  = (const float*)d_in[0];
    const void*  ei = d_in[1];
    const float* W1 = (const float*)d_in[2];
    const float* b1 = (const float*)d_in[3];
    const float* W2 = (const float*)d_in[4];
    const float* b2 = (const float*)d_in[5];
    float* out = (float*)d_out;

    const int Hh  = in_sizes[3];            // 16
    const int Fin = in_sizes[2] / Hh;       // 128
    const int N   = in_sizes[0] / Fin;      // 100000
    const long long twoE = in_sizes[1];
    const int E = (int)(twoE / 2);          // 3200000
    const int nb = (N + BNODES - 1) >> BSHIFT;  // 782 buckets of 128 nodes
    (void)n_in; (void)out_size; (void)ws_size;

    char* p = (char*)d_ws;
    auto alloc = [&](size_t bytes) {
        char* r = p;
        p += (bytes + 63) & ~(size_t)63;
        return r;
    };
    int*      flag  = (int*)alloc(sizeof(int));
    int*      gcur  = (int*)alloc(sizeof(int) * (size_t)nb);
    int*      bbase = (int*)alloc(sizeof(int) * 1024);
    unsigned* pairs = (unsigned*)alloc(sizeof(unsigned) * (size_t)nb * CAP);  // ~19.2 MB
    int*      csr   = (int*)alloc(sizeof(int) * (size_t)E);                   // 12.8 MB
    int*      rowA  = (int*)alloc(sizeof(int) * (size_t)N);
    int*      degA  = (int*)alloc(sizeof(int) * (size_t)N);
    float*    dinv  = (float*)alloc(sizeof(float) * (size_t)N);
    float*    hs1   = (float*)alloc(sizeof(float) * (size_t)N * 16);
    float*    hs2   = (float*)alloc(sizeof(float) * (size_t)N * 8);

    const int pb = (E + P_EPB - 1) / P_EPB;   // 391 place blocks
    const int gb = (N + PT - 1) / PT;         // 196 gemm blocks

    detect_kernel<<<1, 256, 0, stream>>>((const unsigned int*)ei, flag, gcur, nb);
    fused_place_gemm_kernel<<<pb + gb, PT, 0, stream>>>(
        ei, flag, gcur, pairs, x, W1, hs1, E, nb, pb, N);
    scanb_kernel<<<1, 1024, 0, stream>>>(gcur, bbase, nb);
    csr_build_kernel<<<nb, TPB, 0, stream>>>(pairs, gcur, bbase, csr, rowA, degA, dinv, hs1, N);
    int aggBlk = (4 * N + TPB - 1) / TPB;
    agg1_kernel<<<aggBlk, TPB, 0, stream>>>(hs1, csr, rowA, degA, dinv, W2, b1, hs2, N);
    agg2_kernel<<<aggBlk, TPB, 0, stream>>>(hs2, csr, rowA, degA, dinv, b2, out, N);
}

// Round 7
// 119.656 us; speedup vs baseline: 4.9371x; 1.2091x over previous
//
#include <hip/hip_runtime.h>

#define BSHIFT 7
#define BNODES 128
#define BMASK 127
#define CAP 6144
#define PT 512               // fat-kernel threads
#define P_EPB (PT * 16)      // 8192 edges per place block
#define TPB 256

// ---- bf16 pack/unpack helpers (RNE) ----
__device__ __forceinline__ unsigned pkbf2(float a, float b) {
    unsigned ua = __float_as_uint(a), ub = __float_as_uint(b);
    ua = (ua + 0x7fffu + ((ua >> 16) & 1u)) >> 16;
    ub = (ub + 0x7fffu + ((ub >> 16) & 1u)) >> 16;
    return ua | (ub << 16);
}
__device__ __forceinline__ float bflo(unsigned u) { return __uint_as_float(u << 16); }
__device__ __forceinline__ float bfhi(unsigned u) { return __uint_as_float(u & 0xffff0000u); }

// ---------------- index dtype detection + gcur zero ----------------
__global__ void detect_kernel(const unsigned int* __restrict__ w, int* __restrict__ flag,
                              int* __restrict__ gcur, int nb) {
    __shared__ int any;
    if (threadIdx.x == 0) any = 0;
    __syncthreads();
    int nz = 0;
    for (int k = threadIdx.x; k < 1024; k += blockDim.x)
        if (w[2 * k + 1] != 0u) nz = 1;
    if (nz) atomicOr(&any, 1);
    for (int i = threadIdx.x; i < nb; i += blockDim.x) gcur[i] = 0;
    __syncthreads();
    if (threadIdx.x == 0) *flag = (any == 0) ? 1 : 0;  // 1 => int64
}

// ---------------- fused: bucketed placement (write-combined, reg-cached) + layer-1 GEMM ----------------
// blocks [0, pb): placement. blocks [pb, pb+gb): h = x @ W1 (unscaled f32; dinv+bf16 in csr_build).
// smem layout (place path): cnt@0(4096) bbs@4096(4112) cur@8208(4096) ssum@12304(2048) stage@14352(32768)
__global__ __launch_bounds__(PT) void fused_place_gemm_kernel(
    const void* __restrict__ ei, const int* __restrict__ flag,
    int* __restrict__ gcur, unsigned* __restrict__ pairs,
    const float* __restrict__ x, const float* __restrict__ W1,
    float* __restrict__ hs, int E, int nb, int pb, int N) {
    __shared__ alignas(16) char smem[47120];
    int tid = threadIdx.x;
    if ((int)blockIdx.x < pb) {
        int* cnt  = (int*)smem;                  // histogram, then per-bucket global base
        int* bbs  = (int*)(smem + 4096);         // local exclusive offsets (+ sentinel)
        int* cur  = (int*)(smem + 8208);         // scatter cursor
        int* ssum = (int*)(smem + 12304);        // scan scratch
        unsigned* stage = (unsigned*)(smem + 14352);
        const bool is64 = (*flag != 0);
        const long long* e64 = (const long long*)ei;
        const int* e32 = (const int*)ei;
        int e0 = blockIdx.x * P_EPB;
        int tot = E - e0; if (tot > P_EPB) tot = P_EPB;
        for (int b = tid; b < nb; b += PT) cnt[b] = 0;
        __syncthreads();
        // pass 1: read edges ONCE, histogram dst, keep packed value + bucket in registers
        unsigned pk[16];
        int bk[16];
#pragma unroll
        for (int k = 0; k < 16; ++k) {
            int i = tid + k * PT;
            bk[k] = -1;
            if (i < tot) {
                int e = e0 + i;
                int s, d;
                if (is64) { s = (int)e64[e]; d = (int)e64[E + e]; }
                else      { s = e32[e];      d = e32[E + e]; }
                int b = d >> BSHIFT;
                bk[k] = b;
                pk[k] = ((unsigned)s << BSHIFT) | (unsigned)(d & BMASK);
                atomicAdd(&cnt[b], 1);
            }
        }
        __syncthreads();
        // local scan (2 bins/thread) + global reservation
        int t2 = tid * 2;
        int c0 = (t2 < nb) ? cnt[t2] : 0;
        int c1 = (t2 + 1 < nb) ? cnt[t2 + 1] : 0;
        int ts = c0 + c1;
        ssum[tid] = ts;
        __syncthreads();
        for (int off = 1; off < PT; off <<= 1) {
            int v = (tid >= off) ? ssum[tid - off] : 0;
            __syncthreads();
            ssum[tid] += v;
            __syncthreads();
        }
        int excl = ssum[tid] - ts;
        if (tid == PT - 1) bbs[nb] = ssum[PT - 1];   // sentinel = staged total
        int gb0 = 0, gb1 = 0;
        if (t2 < nb && c0) gb0 = atomicAdd(&gcur[t2], c0);
        if (t2 + 1 < nb && c1) gb1 = atomicAdd(&gcur[t2 + 1], c1);
        if (t2 < nb)     { bbs[t2] = excl;          cnt[t2] = gb0;     cur[t2] = 0; }
        if (t2 + 1 < nb) { bbs[t2 + 1] = excl + c0; cnt[t2 + 1] = gb1; cur[t2 + 1] = 0; }
        __syncthreads();
        // pass 2: pure-LDS scatter into bucket-sorted stage
#pragma unroll
        for (int k = 0; k < 16; ++k) {
            if (bk[k] >= 0) {
                int r = atomicAdd(&cur[bk[k]], 1);
                stage[bbs[bk[k]] + r] = pk[k];
            }
        }
        __syncthreads();
        // pass 3: coalesced write of per-bucket runs (binary search for bucket)
        for (int i = tid; i < tot; i += PT) {
            int lo = 0, hi = nb;
            while (hi - lo > 1) { int mid = (lo + hi) >> 1; if (bbs[mid] <= i) lo = mid; else hi = mid; }
            int slot = cnt[lo] + (i - bbs[lo]);
            if (slot < CAP) pairs[(size_t)lo * CAP + slot] = stage[i];
        }
    } else {
        // ---- layer-1 GEMM: h = x @ W1 (unscaled f32) ----
        float* Ws = (float*)smem;
        for (int i = tid; i < 2048; i += PT) Ws[i] = W1[i];
        __syncthreads();
        int n = ((int)blockIdx.x - pb) * PT + tid;
        if (n >= N) return;
        const float4* xp = (const float4*)(x + (size_t)n * 128);
        float a[16];
#pragma unroll
        for (int j = 0; j < 16; ++j) a[j] = 0.f;
#pragma unroll 4
        for (int k4 = 0; k4 < 32; ++k4) {
            float4 xv = xp[k4];
            const float* wr = &Ws[k4 * 64];
#pragma unroll
            for (int j = 0; j < 16; ++j) a[j] += xv.x * wr[j];
#pragma unroll
            for (int j = 0; j < 16; ++j) a[j] += xv.y * wr[16 + j];
#pragma unroll
            for (int j = 0; j < 16; ++j) a[j] += xv.z * wr[32 + j];
#pragma unroll
            for (int j = 0; j < 16; ++j) a[j] += xv.w * wr[48 + j];
        }
        float4* hp = (float4*)(hs + (size_t)n * 16);
#pragma unroll
        for (int j4 = 0; j4 < 4; ++j4) {
            float4 v;
            v.x = a[j4 * 4 + 0]; v.y = a[j4 * 4 + 1];
            v.z = a[j4 * 4 + 2]; v.w = a[j4 * 4 + 3];
            hp[j4] = v;
        }
    }
}

// ---------------- bucket base offsets (exclusive scan of bucket sizes) ----------------
__global__ __launch_bounds__(1024) void scanb_kernel(const int* __restrict__ gcur,
                                                     int* __restrict__ bbase, int nb) {
    __shared__ int sh[1024];
    int t = threadIdx.x;
    int v = 0;
    if (t < nb) { v = gcur[t]; if (v > CAP) v = CAP; }
    sh[t] = v;
    __syncthreads();
    for (int off = 1; off < 1024; off <<= 1) {
        int u = (t >= off) ? sh[t - off] : 0;
        __syncthreads();
        sh[t] += u;
        __syncthreads();
    }
    if (t < nb) bbase[t] = sh[t] - v;  // exclusive
}

// ---------------- counting sort -> CSR + deg + bf16 scale-pack of hs1 ----------------
__global__ __launch_bounds__(TPB) void csr_build_kernel(
    const unsigned* __restrict__ pairs, const int* __restrict__ gcur,
    const int* __restrict__ bbase, int* __restrict__ csr,
    int* __restrict__ row, int* __restrict__ degA,
    const float* __restrict__ hs1f, uint4* __restrict__ hs1b, int N) {
    __shared__ int hist[BNODES];
    __shared__ int sc[BNODES];
    __shared__ int cur[BNODES];
    __shared__ int stage[CAP];
    int tid = threadIdx.x;
    int b = blockIdx.x;
    if (tid < BNODES) hist[tid] = 0;
    __syncthreads();
    int cnt = gcur[b]; if (cnt > CAP) cnt = CAP;
    int base = bbase[b];
    const unsigned* sl = pairs + (size_t)b * CAP;
    for (int i = tid; i < cnt; i += TPB)
        atomicAdd(&hist[sl[i] & BMASK], 1);
    __syncthreads();
    if (tid < BNODES) sc[tid] = hist[tid];
    __syncthreads();
    for (int off = 1; off < BNODES; off <<= 1) {
        int u = (tid < BNODES && tid >= off) ? sc[tid - off] : 0;
        __syncthreads();
        if (tid < BNODES) sc[tid] += u;
        __syncthreads();
    }
    if (tid < BNODES) {
        int excl = sc[tid] - hist[tid];
        sc[tid] = excl;
        cur[tid] = 0;
        int node = (b << BSHIFT) + tid;
        if (node < N) {
            row[node]  = base + excl;
            degA[node] = hist[tid];
        }
    }
    __syncthreads();
    for (int i = tid; i < cnt; i += TPB) {
        unsigned val = sl[i];
        int l = val & BMASK;
        int r = atomicAdd(&cur[l], 1);
        stage[sc[l] + r] = (int)(val >> BSHIFT);
    }
    __syncthreads();
    for (int i = tid; i < cnt; i += TPB)
        csr[base + i] = stage[i];
    // scale-by-dinv + pack to bf16: hs1b[node] = bf16(dinv * hs1f[node]) (coalesced)
    int nodeBase = b << BSHIFT;
    {
        int ln = tid >> 1, half = tid & 1;     // 256 threads = 128 nodes x 2 halves
        int node = nodeBase + ln;
        if (node < N) {
            float s = rsqrtf((float)(hist[ln] + 1));   // +1 self-loop
            const float4* F = (const float4*)(hs1f + (size_t)node * 16);
            float4 f0 = F[half * 2], f1 = F[half * 2 + 1];
            uint4 u;
            u.x = pkbf2(f0.x * s, f0.y * s); u.y = pkbf2(f0.z * s, f0.w * s);
            u.z = pkbf2(f1.x * s, f1.y * s); u.w = pkbf2(f1.z * s, f1.w * s);
            hs1b[(size_t)node * 2 + half] = u;
        }
    }
}

// ---------------- agg1: per-node bf16 register gather (4 lanes/node) + fused layer2 ----------------
__global__ __launch_bounds__(TPB) void agg1_kernel(
    const uint4* __restrict__ hs1b, const int* __restrict__ csr,
    const int* __restrict__ row, const int* __restrict__ degA,
    const float* __restrict__ W2, const float* __restrict__ b1,
    uint4* __restrict__ hs2b, int N) {
    __shared__ float Ws[112];
    __shared__ float bs[16];
    int tid = threadIdx.x;
    if (tid < 112) Ws[tid] = W2[tid];
    if (tid < 16) bs[tid] = b1[tid];
    __syncthreads();
    int g = blockIdx.x * TPB + tid;
    int n = g >> 2, quarter = g & 3;
    int st = 0, cnt = 0;
    if (n < N) { st = row[n]; cnt = degA[n]; }
    float acc[16];
#pragma unroll
    for (int j = 0; j < 16; ++j) acc[j] = 0.f;
    int i = st + quarter, end = st + cnt;
    for (; i + 4 < end; i += 8) {
        int s0 = csr[i], s1 = csr[i + 4];
        uint4 g0 = hs1b[(size_t)s0 * 2], g1 = hs1b[(size_t)s0 * 2 + 1];
        uint4 h0 = hs1b[(size_t)s1 * 2], h1 = hs1b[(size_t)s1 * 2 + 1];
        acc[0]  += bflo(g0.x) + bflo(h0.x); acc[1]  += bfhi(g0.x) + bfhi(h0.x);
        acc[2]  += bflo(g0.y) + bflo(h0.y); acc[3]  += bfhi(g0.y) + bfhi(h0.y);
        acc[4]  += bflo(g0.z) + bflo(h0.z); acc[5]  += bfhi(g0.z) + bfhi(h0.z);
        acc[6]  += bflo(g0.w) + bflo(h0.w); acc[7]  += bfhi(g0.w) + bfhi(h0.w);
        acc[8]  += bflo(g1.x) + bflo(h1.x); acc[9]  += bfhi(g1.x) + bfhi(h1.x);
        acc[10] += bflo(g1.y) + bflo(h1.y); acc[11] += bfhi(g1.y) + bfhi(h1.y);
        acc[12] += bflo(g1.z) + bflo(h1.z); acc[13] += bfhi(g1.z) + bfhi(h1.z);
        acc[14] += bflo(g1.w) + bflo(h1.w); acc[15] += bfhi(g1.w) + bfhi(h1.w);
    }
    if (i < end) {
        int s0 = csr[i];
        uint4 g0 = hs1b[(size_t)s0 * 2], g1 = hs1b[(size_t)s0 * 2 + 1];
        acc[0]  += bflo(g0.x); acc[1]  += bfhi(g0.x);
        acc[2]  += bflo(g0.y); acc[3]  += bfhi(g0.y);
        acc[4]  += bflo(g0.z); acc[5]  += bfhi(g0.z);
        acc[6]  += bflo(g0.w); acc[7]  += bfhi(g0.w);
        acc[8]  += bflo(g1.x); acc[9]  += bfhi(g1.x);
        acc[10] += bflo(g1.y); acc[11] += bfhi(g1.y);
        acc[12] += bflo(g1.z); acc[13] += bfhi(g1.z);
        acc[14] += bflo(g1.w); acc[15] += bfhi(g1.w);
    }
#pragma unroll
    for (int j = 0; j < 16; ++j) {
        acc[j] += __shfl_xor(acc[j], 1);
        acc[j] += __shfl_xor(acc[j], 2);
    }
    if (quarter == 0 && n < N) {
        float sc = rsqrtf((float)(cnt + 1));
        uint4 sA = hs1b[(size_t)n * 2], sB = hs1b[(size_t)n * 2 + 1];
        float self[16] = {bflo(sA.x), bfhi(sA.x), bflo(sA.y), bfhi(sA.y),
                          bflo(sA.z), bfhi(sA.z), bflo(sA.w), bfhi(sA.w),
                          bflo(sB.x), bfhi(sB.x), bflo(sB.y), bfhi(sB.y),
                          bflo(sB.z), bfhi(sB.z), bflo(sB.w), bfhi(sB.w)};
        float v[16];
#pragma unroll
        for (int j = 0; j < 16; ++j)
            v[j] = fmaxf(0.f, sc * (acc[j] + self[j]) + bs[j]);
        float h[7];
#pragma unroll
        for (int j = 0; j < 7; ++j) h[j] = 0.f;
#pragma unroll
        for (int k = 0; k < 16; ++k)
#pragma unroll
            for (int j = 0; j < 7; ++j) h[j] += v[k] * Ws[k * 7 + j];
        uint4 u;
        u.x = pkbf2(h[0] * sc, h[1] * sc);
        u.y = pkbf2(h[2] * sc, h[3] * sc);
        u.z = pkbf2(h[4] * sc, h[5] * sc);
        u.w = pkbf2(h[6] * sc, 0.f);
        hs2b[n] = u;
    }
}

// ---------------- agg2: per-node bf16 gather (4 lanes/node, 1 uint4/edge) + bias/log-softmax ----------------
__global__ __launch_bounds__(TPB) void agg2_kernel(
    const uint4* __restrict__ hs2b, const int* __restrict__ csr,
    const int* __restrict__ row, const int* __restrict__ degA,
    const float* __restrict__ b2, float* __restrict__ out, int N) {
    __shared__ float bs[8];
    if (threadIdx.x < 7) bs[threadIdx.x] = b2[threadIdx.x];
    __syncthreads();
    int g = blockIdx.x * TPB + threadIdx.x;
    int n = g >> 2, quarter = g & 3;
    int st = 0, cnt = 0;
    if (n < N) { st = row[n]; cnt = degA[n]; }
    float acc[7];
#pragma unroll
    for (int j = 0; j < 7; ++j) acc[j] = 0.f;
    int i = st + quarter, end = st + cnt;
    for (; i + 4 < end; i += 8) {
        int s0 = csr[i], s1 = csr[i + 4];
        uint4 q = hs2b[s0];
        uint4 r = hs2b[s1];
        acc[0] += bflo(q.x) + bflo(r.x); acc[1] += bfhi(q.x) + bfhi(r.x);
        acc[2] += bflo(q.y) + bflo(r.y); acc[3] += bfhi(q.y) + bfhi(r.y);
        acc[4] += bflo(q.z) + bflo(r.z); acc[5] += bfhi(q.z) + bfhi(r.z);
        acc[6] += bflo(q.w) + bflo(r.w);
    }
    if (i < end) {
        uint4 q = hs2b[csr[i]];
        acc[0] += bflo(q.x); acc[1] += bfhi(q.x);
        acc[2] += bflo(q.y); acc[3] += bfhi(q.y);
        acc[4] += bflo(q.z); acc[5] += bfhi(q.z);
        acc[6] += bflo(q.w);
    }
#pragma unroll
    for (int j = 0; j < 7; ++j) {
        acc[j] += __shfl_xor(acc[j], 1);
        acc[j] += __shfl_xor(acc[j], 2);
    }
    if (quarter == 0 && n < N) {
        float sc = rsqrtf((float)(cnt + 1));
        uint4 q = hs2b[n];
        float self[7] = {bflo(q.x), bfhi(q.x), bflo(q.y), bfhi(q.y),
                         bflo(q.z), bfhi(q.z), bflo(q.w)};
        float v[7];
#pragma unroll
        for (int j = 0; j < 7; ++j)
            v[j] = sc * (acc[j] + self[j]) + bs[j];
        float m = v[0];
#pragma unroll
        for (int j = 1; j < 7; ++j) m = fmaxf(m, v[j]);
        float ssum = 0.f;
#pragma unroll
        for (int j = 0; j < 7; ++j) ssum += __expf(v[j] - m);
        float l = m + __logf(ssum);
        float* op = out + (size_t)n * 7;
#pragma unroll
        for (int j = 0; j < 7; ++j) op[j] = v[j] - l;
    }
}

extern "C" void kernel_launch(void* const* d_in, const int* in_sizes, int n_in,
                              void* d_out, int out_size, void* d_ws, size_t ws_size,
                              hipStream_t stream) {
    const float* x  = (const float*)d_in[0];
    const void*  ei = d_in[1];
    const float* W1 = (const float*)d_in[2];
    const float* b1 = (const float*)d_in[3];
    const float* W2 = (const float*)d_in[4];
    const float* b2 = (const float*)d_in[5];
    float* out = (float*)d_out;

    const int Hh  = in_sizes[3];            // 16
    const int Fin = in_sizes[2] / Hh;       // 128
    const int N   = in_sizes[0] / Fin;      // 100000
    const long long twoE = in_sizes[1];
    const int E = (int)(twoE / 2);          // 3200000
    const int nb = (N + BNODES - 1) >> BSHIFT;  // 782 buckets of 128 nodes
    (void)n_in; (void)out_size; (void)ws_size;

    char* p = (char*)d_ws;
    auto alloc = [&](size_t bytes) {
        char* r = p;
        p += (bytes + 63) & ~(size_t)63;
        return r;
    };
    int*      flag  = (int*)alloc(sizeof(int));
    int*      gcur  = (int*)alloc(sizeof(int) * (size_t)nb);
    int*      bbase = (int*)alloc(sizeof(int) * 1024);
    unsigned* pairs = (unsigned*)alloc(sizeof(unsigned) * (size_t)nb * CAP);  // ~19.2 MB
    int*      csr   = (int*)alloc(sizeof(int) * (size_t)E);                   // 12.8 MB
    int*      rowA  = (int*)alloc(sizeof(int) * (size_t)N);
    int*      degA  = (int*)alloc(sizeof(int) * (size_t)N);
    float*    hs1f  = (float*)alloc(sizeof(float) * (size_t)N * 16);          // 6.4 MB f32
    uint4*    hs1b  = (uint4*)alloc(32 * (size_t)N);                          // 3.2 MB bf16
    uint4*    hs2b  = (uint4*)alloc(16 * (size_t)N);                          // 1.6 MB bf16

    const int pb = (E + P_EPB - 1) / P_EPB;   // 391 place blocks
    const int gb = (N + PT - 1) / PT;         // 196 gemm blocks

    detect_kernel<<<1, 256, 0, stream>>>((const unsigned int*)ei, flag, gcur, nb);
    fused_place_gemm_kernel<<<pb + gb, PT, 0, stream>>>(
        ei, flag, gcur, pairs, x, W1, hs1f, E, nb, pb, N);
    scanb_kernel<<<1, 1024, 0, stream>>>(gcur, bbase, nb);
    csr_build_kernel<<<nb, TPB, 0, stream>>>(pairs, gcur, bbase, csr, rowA, degA, hs1f, hs1b, N);
    int aggBlk = (4 * N + TPB - 1) / TPB;
    agg1_kernel<<<aggBlk, TPB, 0, stream>>>(hs1b, csr, rowA, degA, W2, b1, hs2b, N);
    agg2_kernel<<<aggBlk, TPB, 0, stream>>>(hs2b, csr, rowA, degA, b2, out, N);
}